// Round 9
// baseline (231.444 us; speedup 1.0000x reference)
//
#include <hip/hip_runtime.h>
#include <math.h>

#define B_ 4
#define N_ 4096
#define BN_ (B_*N_)
#define NT 64                 /* 64 j/i tiles */
#define NCH 8                 /* c-chunks per i-tile */

typedef __bf16 v8bf __attribute__((ext_vector_type(8)));
typedef unsigned short u16x8 __attribute__((ext_vector_type(8)));
typedef float v4f __attribute__((ext_vector_type(4)));

#define LOG2E 1.44269504088896340736f
#define CPROX (-50.0f*LOG2E)            /* -1/(2*sigma^2) * log2(e) */
#define INVSQRT3 0.57735026918962576f
/* smoothstep sigmoid approx: sigmoid(5(s-tau)) ~ S((s-tau)/1.4 + 0.5) */
#define GS (1.0f/1.4f)
#define GC_FLOW  (0.5f - 0.8f*GS)
#define GC_COLOR (0.5f - 0.7f*GS)
#define GC_PROX  (0.5f - 0.5f*GS)

__device__ __forceinline__ float fexp2(float x){ return __builtin_amdgcn_exp2f(x); }
__device__ __forceinline__ float fsqrt(float x){ return __builtin_amdgcn_sqrtf(x); }

// ---------------- prep: normalize features -> bf16, per-point scalars ----------------
extern "C" __global__ __launch_bounds__(256) void prep_k(
    const float* __restrict__ flow, const float* __restrict__ color,
    const float* __restrict__ coord, const float* __restrict__ feat,
    unsigned short* __restrict__ fn, float* __restrict__ scal)
{
  const int wave = blockIdx.x*4 + (threadIdx.x>>6);
  const int lane = threadIdx.x & 63;
  float v = feat[(size_t)wave*64 + lane];
  float ss = v*v;
  #pragma unroll
  for (int d=32; d; d>>=1) ss += __shfl_xor(ss, d);
  float sc = 1.0f/(sqrtf(ss)+1e-7f);     // matches ref: f/(||f||+1e-7)
  float x = v*sc;
  unsigned u = __builtin_bit_cast(unsigned, x);
  unsigned r = (u + 0x7fffu + ((u>>16)&1u)) >> 16;   // RN-even f32->bf16
  fn[(size_t)wave*64+lane] = (unsigned short)r;
  if (lane==0) {
    float fx=flow[wave*3+0], fy=flow[wave*3+1], fz=flow[wave*3+2];
    float rn = 1.0f/sqrtf(fx*fx+fy*fy+fz*fz + 1e-8f);
    const float k = 1.0f/255.0f;
    float cx=color[wave*3+0]*k, cy=color[wave*3+1]*k, cz=color[wave*3+2]*k;
    float px=coord[wave*3+0], py=coord[wave*3+1], pz=coord[wave*3+2];
    float* o = scal + (size_t)wave*12;
    o[0]=fx*rn; o[1]=fy*rn; o[2]=fz*rn;
    o[3]=cx; o[4]=cy; o[5]=cz;
    o[6]=cx*cx+cy*cy+cz*cz;
    o[7]=px; o[8]=py; o[9]=pz;
    o[10]=px*px+py*py+pz*pz;
    o[11]=0.f;
  }
}

// ---------- main: symmetric ring tiles, row + column scatter, no atomics ----------
// block (b, ti, k): j-tiles tj=(ti+c)&63 for c in [4k,4k+4), k==7 also c=32 if ti<32.
// Every unordered tile-pair computed exactly once (c=0 diag: rows only).
extern "C" __global__ __launch_bounds__(256,3) void main_k(
    const unsigned short* __restrict__ fn, const float* __restrict__ scal,
    float* __restrict__ part_row, float* __restrict__ part2)
{
  __shared__ unsigned short fnj[64*64];   // 8 KB, XOR-swizzled rows (128B each)
  __shared__ float scj[64*12];            // 3 KB
  __shared__ float colacc[4][64][6];      // 6 KB per-wave column partials

  const int ti = blockIdx.x & 63;
  const int k  = blockIdx.x >> 6;         // 0..7
  const int b  = blockIdx.y;
  const int nt = (k<7) ? 4 : ((ti<32) ? 5 : 4);
  const int c0 = k*4;

  const int tid  = threadIdx.x;
  const int w    = tid >> 6;
  const int lane = tid & 63;
  const int g    = lane >> 4;
  const int col  = lane & 15;
  const int irow0 = ti*64 + w*16;

  const unsigned short* fnb = fn + (size_t)b*N_*64;
  const float* scb = scal + (size_t)b*N_*12;

  // A fragments: row = lane&15, kk = (lane>>4)*8 + e (two K=32 halves), held in regs
  const int arow = irow0 + col;
  v8bf a0 = __builtin_bit_cast(v8bf, *(const u16x8*)(fnb + (size_t)arow*64 + g*8));
  v8bf a1 = __builtin_bit_cast(v8bf, *(const u16x8*)(fnb + (size_t)arow*64 + 32 + g*8));

  // i-side scalars for this lane's 4 output rows (row = g*4 + r)
  float fhi[4][3], n2c[4][3], n2p[4][3], csqi[4], psqi[4];
  #pragma unroll
  for (int r=0;r<4;++r) {
    const float* s = scb + (size_t)(irow0 + g*4 + r)*12;
    v4f s0 = *(const v4f*)(s), s1 = *(const v4f*)(s+4), s2 = *(const v4f*)(s+8);
    fhi[r][0]=s0.x; fhi[r][1]=s0.y; fhi[r][2]=s0.z;
    n2c[r][0]=-2.f*s0.w; n2c[r][1]=-2.f*s1.x; n2c[r][2]=-2.f*s1.y;
    csqi[r]=s1.z;
    n2p[r][0]=-2.f*s1.w; n2p[r][1]=-2.f*s2.x; n2p[r][2]=-2.f*s2.y;
    psqi[r]=s2.z;
  }

  float spa[3][4], sma[3][4];
  #pragma unroll
  for (int l=0;l<3;++l)
    #pragma unroll
    for (int r=0;r<4;++r){ spa[l][r]=0.f; sma[l][r]=0.f; }

  for (int tt=0; tt<nt; ++tt) {
    const int c  = c0 + tt;
    const int tj = (ti + c) & 63;
    const unsigned short* fng = fnb + (size_t)tj*64*64;
    const float* scg = scb + (size_t)tj*64*12;

    __syncthreads();                      // protect fnj/scj/colacc from prior tile
    #pragma unroll
    for (int q=0;q<2;++q) {               // stage 64 rows x 128B of fn, swizzled
      int idx = tid + q*256;
      int row = idx>>3, seg = idx&7;
      const float4 src = *(const float4*)(fng + (size_t)row*64 + seg*8);
      *(float4*)((char*)fnj + row*128 + ((seg*16) ^ ((row&7)<<4))) = src;
    }
    if (tid < 192) {                      // stage 64 rows x 48B of scalars
      int row = tid/3, seg = tid - row*3;
      *(float4*)(scj + row*12 + seg*4) = *(const float4*)(scg + (size_t)row*12 + seg*4);
    }
    __syncthreads();

    #pragma unroll
    for (int sub=0; sub<4; ++sub) {
      const int jloc = sub*16 + col;
      const int sw = (jloc&7)<<4;
      const char* rowp = (const char*)fnj + jloc*128;
      v8bf b0 = __builtin_bit_cast(v8bf, *(const u16x8*)(rowp + ((g*16) ^ sw)));
      v8bf b1 = __builtin_bit_cast(v8bf, *(const u16x8*)(rowp + ((64 + g*16) ^ sw)));
      v4f j0 = *(const v4f*)(scj + jloc*12);
      v4f j1 = *(const v4f*)(scj + jloc*12 + 4);
      v4f j2 = *(const v4f*)(scj + jloc*12 + 8);

      v4f acc = {0.f,0.f,0.f,0.f};
      acc = __builtin_amdgcn_mfma_f32_16x16x32_bf16(a0, b0, acc, 0,0,0);
      acc = __builtin_amdgcn_mfma_f32_16x16x32_bf16(a1, b1, acc, 0,0,0);

      float cp0=0.f, cp1=0.f, cp2=0.f, cp3=0.f, cp4=0.f, cp5=0.f;

      #pragma unroll
      for (int r=0;r<4;++r) {
        const float fs = acc[r];                    // feature cosine (i=g*4+r, j=jloc)
        const float sf = fhi[r][0]*j0.x + fhi[r][1]*j0.y + fhi[r][2]*j0.z;  // flow cos
        float d2c = csqi[r] + j1.z;
        d2c = fmaf(n2c[r][0], j0.w, d2c);
        d2c = fmaf(n2c[r][1], j1.x, d2c);
        d2c = fmaf(n2c[r][2], j1.y, d2c);
        const float scl = fmaf(fsqrt(fmaxf(d2c,0.f)), -INVSQRT3, 1.0f);      // color sim
        float d2p = psqi[r] + j2.z;
        d2p = fmaf(n2p[r][0], j1.w, d2p);
        d2p = fmaf(n2p[r][1], j2.x, d2p);
        d2p = fmaf(n2p[r][2], j2.y, d2p);
        const float spr = fexp2(fsqrt(fmaxf(d2p,0.f)) * CPROX);              // prox sim
        const float fsl = fs * LOG2E;
        const float E2 = fexp2(-fsl);               // exp(-fs), shared by 3 losses
        {
          float tt2 = __builtin_fminf(__builtin_fmaxf(fmaf(sf, GS, GC_FLOW), 0.f), 1.f);
          float gp = tt2*tt2*fmaf(tt2, -2.f, 3.f);  // ~sigmoid(5(s-tau))
          float e1 = fexp2(fsl*gp);                 // exp(fs*g+)
          float e2 = E2*e1;                         // exp(-fs*g-)
          spa[0][r] += e1; sma[0][r] += e2; cp0 += e1; cp1 += e2;
        }
        {
          float tt2 = __builtin_fminf(__builtin_fmaxf(fmaf(scl, GS, GC_COLOR), 0.f), 1.f);
          float gp = tt2*tt2*fmaf(tt2, -2.f, 3.f);
          float e1 = fexp2(fsl*gp);
          float e2 = E2*e1;
          spa[1][r] += e1; sma[1][r] += e2; cp2 += e1; cp3 += e2;
        }
        {
          float tt2 = __builtin_fminf(__builtin_fmaxf(fmaf(spr, GS, GC_PROX), 0.f), 1.f);
          float gp = tt2*tt2*fmaf(tt2, -2.f, 3.f);
          float e1 = fexp2(fsl*gp);
          float e2 = E2*e1;
          spa[2][r] += e1; sma[2][r] += e2; cp4 += e1; cp5 += e2;
        }
      }

      // column partials: reduce the 4 g-groups (same 16 j-columns per group)
      cp0 += __shfl_xor(cp0,16); cp0 += __shfl_xor(cp0,32);
      cp1 += __shfl_xor(cp1,16); cp1 += __shfl_xor(cp1,32);
      cp2 += __shfl_xor(cp2,16); cp2 += __shfl_xor(cp2,32);
      cp3 += __shfl_xor(cp3,16); cp3 += __shfl_xor(cp3,32);
      cp4 += __shfl_xor(cp4,16); cp4 += __shfl_xor(cp4,32);
      cp5 += __shfl_xor(cp5,16); cp5 += __shfl_xor(cp5,32);
      if (lane < 16) {
        float* ca = colacc[w][jloc];
        ca[0]=cp0; ca[1]=cp1; ca[2]=cp2; ca[3]=cp3; ca[4]=cp4; ca[5]=cp5;
      }
    }
    __syncthreads();
    if (c > 0) {                          // flush columns (diag tile: rows cover all)
      #pragma unroll
      for (int s = tid; s < 384; s += 256) {
        int jl = s/6, kk = s - 6*jl;
        float v = colacc[0][jl][kk]+colacc[1][jl][kk]+colacc[2][jl][kk]+colacc[3][jl][kk];
        part2[(((size_t)b*32 + (c-1))*N_ + tj*64 + jl)*6 + kk] = v;
      }
    }
  }

  // rows: reduce the 16 j-columns held across the 16-lane group
  #pragma unroll
  for (int l=0;l<3;++l)
    #pragma unroll
    for (int r=0;r<4;++r) {
      float a=spa[l][r], cc=sma[l][r];
      #pragma unroll
      for (int d=1; d<16; d<<=1){ a += __shfl_xor(a,d); cc += __shfl_xor(cc,d); }
      spa[l][r]=a; sma[l][r]=cc;
    }
  if (col==0) {
    #pragma unroll
    for (int r=0;r<4;++r) {
      float* o = part_row + (((size_t)b*NCH + k)*N_ + irow0 + g*4 + r)*6;
      o[0]=spa[0][r]; o[1]=sma[0][r];
      o[2]=spa[1][r]; o[3]=sma[1][r];
      o[4]=spa[2][r]; o[5]=sma[2][r];
    }
  }
}

// ---------------- finalize: combine row+col partials, log1p + mean ----------------
extern "C" __global__ __launch_bounds__(256) void fin1_k(
    const float* __restrict__ part_row, const float* __restrict__ part2,
    float* __restrict__ partial)
{
  const int pt = blockIdx.x*256 + threadIdx.x;   // b*N_ + i
  const int b = pt >> 12;
  const int i = pt & (N_-1);
  float s[6] = {0.f,0.f,0.f,0.f,0.f,0.f};
  #pragma unroll
  for (int kc=0;kc<NCH;++kc) {
    const float* pp = part_row + (((size_t)b*NCH + kc)*N_ + i)*6;
    #pragma unroll
    for (int q=0;q<6;++q) s[q] += pp[q];
  }
  for (int c=1;c<=31;++c) {
    const float* pp = part2 + (((size_t)b*32 + (c-1))*N_ + i)*6;
    #pragma unroll
    for (int q=0;q<6;++q) s[q] += pp[q];
  }
  if (i >= 2048) {   // c=32 slots written only for j-tiles >= 32
    const float* pp = part2 + (((size_t)b*32 + 31)*N_ + i)*6;
    #pragma unroll
    for (int q=0;q<6;++q) s[q] += pp[q];
  }
  float acc = log1pf(s[0]) + log1pf(s[1]) + log1pf(s[2])
            + log1pf(s[3]) + log1pf(s[4]) + log1pf(s[5]);
  #pragma unroll
  for (int d=32; d; d>>=1) acc += __shfl_xor(acc, d);
  __shared__ float wsum[4];
  if ((threadIdx.x&63)==0) wsum[threadIdx.x>>6] = acc;
  __syncthreads();
  if (threadIdx.x==0) partial[blockIdx.x] = wsum[0]+wsum[1]+wsum[2]+wsum[3];
}

extern "C" __global__ void fin2_k(const float* __restrict__ partial, float* __restrict__ out)
{
  float acc = partial[threadIdx.x];   // 64 threads
  #pragma unroll
  for (int d=32; d; d>>=1) acc += __shfl_xor(acc, d);
  if (threadIdx.x==0) out[0] = -acc * (1.0f/(float)BN_);
}

extern "C" void kernel_launch(void* const* d_in, const int* in_sizes, int n_in,
                              void* d_out, int out_size, void* d_ws, size_t ws_size,
                              hipStream_t stream)
{
  const float* flow  = (const float*)d_in[0];
  const float* color = (const float*)d_in[1];
  const float* coord = (const float*)d_in[2];
  const float* feat  = (const float*)d_in[3];
  char* ws = (char*)d_ws;
  unsigned short* fn = (unsigned short*)ws;                       // 2 MB
  float* scal     = (float*)(ws + 2097152);                       // 768 KB
  float* part_row = (float*)(ws + 2883584);                       // 3 MB  [b][8][N][6]
  float* part2    = (float*)(ws + 6029312);                       // 12 MB [b][32][N][6]
  float* partial  = (float*)(ws + 18612224);                      // 256 B
  float* outp = (float*)d_out;
  hipLaunchKernelGGL(prep_k, dim3(BN_/4), dim3(256), 0, stream,
                     flow, color, coord, feat, fn, scal);
  hipLaunchKernelGGL(main_k, dim3(NT*NCH, B_), dim3(256), 0, stream,
                     fn, scal, part_row, part2);
  hipLaunchKernelGGL(fin1_k, dim3(BN_/256), dim3(256), 0, stream,
                     part_row, part2, partial);
  hipLaunchKernelGGL(fin2_k, dim3(1), dim3(64), 0, stream, partial, outp);
}

// Round 10
// 117.999 us; speedup vs baseline: 1.9614x; 1.9614x over previous
//
#include <hip/hip_runtime.h>
#include <math.h>

#define B_ 4
#define N_ 4096
#define BN_ (B_*N_)
#define NT 64                 /* 64 tiles of 64 rows */
#define NCH 8                 /* c-chunks per i-tile */

typedef __bf16 v8bf __attribute__((ext_vector_type(8)));
typedef unsigned short u16x8 __attribute__((ext_vector_type(8)));
typedef float v4f __attribute__((ext_vector_type(4)));

#define LOG2E 1.44269504088896340736f
#define CPROX (-50.0f*LOG2E)            /* -1/(2*sigma^2) * log2(e) */
#define INVSQRT3 0.57735026918962576f
/* smoothstep sigmoid approx: sigmoid(5(s-tau)) ~ S((s-tau)/1.4 + 0.5) */
#define GS (1.0f/1.4f)
#define GC_FLOW  (0.5f - 0.8f*GS)
#define GC_COLOR (0.5f - 0.7f*GS)
#define GC_PROX  (0.5f - 0.5f*GS)

__device__ __forceinline__ float fexp2(float x){ return __builtin_amdgcn_exp2f(x); }
__device__ __forceinline__ float fsqrt(float x){ return __builtin_amdgcn_sqrtf(x); }

// ---------------- prep: normalize features -> bf16, per-point scalars ----------------
extern "C" __global__ __launch_bounds__(256) void prep_k(
    const float* __restrict__ flow, const float* __restrict__ color,
    const float* __restrict__ coord, const float* __restrict__ feat,
    unsigned short* __restrict__ fn, float* __restrict__ scal)
{
  const int wave = blockIdx.x*4 + (threadIdx.x>>6);
  const int lane = threadIdx.x & 63;
  float v = feat[(size_t)wave*64 + lane];
  float ss = v*v;
  #pragma unroll
  for (int d=32; d; d>>=1) ss += __shfl_xor(ss, d);
  float sc = 1.0f/(sqrtf(ss)+1e-7f);     // matches ref: f/(||f||+1e-7)
  float x = v*sc;
  unsigned u = __builtin_bit_cast(unsigned, x);
  unsigned r = (u + 0x7fffu + ((u>>16)&1u)) >> 16;   // RN-even f32->bf16
  fn[(size_t)wave*64+lane] = (unsigned short)r;
  if (lane==0) {
    float fx=flow[wave*3+0], fy=flow[wave*3+1], fz=flow[wave*3+2];
    float rn = 1.0f/sqrtf(fx*fx+fy*fy+fz*fz + 1e-8f);
    const float k = 1.0f/255.0f;
    float cx=color[wave*3+0]*k, cy=color[wave*3+1]*k, cz=color[wave*3+2]*k;
    float px=coord[wave*3+0], py=coord[wave*3+1], pz=coord[wave*3+2];
    float* o = scal + (size_t)wave*12;
    o[0]=fx*rn; o[1]=fy*rn; o[2]=fz*rn;
    o[3]=cx; o[4]=cy; o[5]=cz;
    o[6]=cx*cx+cy*cy+cz*cz;
    o[7]=px; o[8]=py; o[9]=pz;
    o[10]=px*px+py*py+pz*pz;
    o[11]=0.f;
  }
}

// ---------- main: symmetric ring tiles, row + column scatter, no atomics ----------
// block (b, ti, k): j-tiles tj=(ti+c)&63, c in [4k,4k+4) for k<7; k==7: c=28..32.
// c=0 (diag) and c=32 (antipode, computed from both ends) are rows-only.
// Column flush only for c in [1,31]: every unordered tile-pair counted once.
extern "C" __global__ __launch_bounds__(256,2) void main_k(
    const unsigned short* __restrict__ fn, const float* __restrict__ scal,
    float* __restrict__ part_row, float* __restrict__ part2)
{
  __shared__ unsigned short fnj[64*64];   // 8 KB, XOR-swizzled rows (128B each)
  __shared__ float scj[64*12];            // 3 KB
  __shared__ float colacc[4][64][6];      // 6 KB per-wave column partials

  const int ti = blockIdx.x & 63;
  const int k  = blockIdx.x >> 6;         // 0..7
  const int b  = blockIdx.y;
  const int nt = (k==7) ? 5 : 4;
  const int c0 = k*4;

  const int tid  = threadIdx.x;
  const int w    = tid >> 6;
  const int lane = tid & 63;
  const int g    = lane >> 4;
  const int col  = lane & 15;
  const int irow0 = ti*64 + w*16;

  const unsigned short* fnb = fn + (size_t)b*N_*64;
  const float* scb = scal + (size_t)b*N_*12;

  // A fragments: row = lane&15, kk = (lane>>4)*8 + e (two K=32 halves), held in regs
  const int arow = irow0 + col;
  v8bf a0 = __builtin_bit_cast(v8bf, *(const u16x8*)(fnb + (size_t)arow*64 + g*8));
  v8bf a1 = __builtin_bit_cast(v8bf, *(const u16x8*)(fnb + (size_t)arow*64 + 32 + g*8));

  // i-side scalars, raw form (9/row, not 11 — R9 spill lesson)
  float fhi[4][3], ci[4][3], pi[4][3];
  #pragma unroll
  for (int r=0;r<4;++r) {
    const float* s = scb + (size_t)(irow0 + g*4 + r)*12;
    v4f s0 = *(const v4f*)(s), s1 = *(const v4f*)(s+4), s2 = *(const v4f*)(s+8);
    fhi[r][0]=s0.x; fhi[r][1]=s0.y; fhi[r][2]=s0.z;
    ci[r][0]=s0.w;  ci[r][1]=s1.x;  ci[r][2]=s1.y;
    pi[r][0]=s1.w;  pi[r][1]=s2.x;  pi[r][2]=s2.y;
  }

  float spa[3][4], sma[3][4];
  #pragma unroll
  for (int l=0;l<3;++l)
    #pragma unroll
    for (int r=0;r<4;++r){ spa[l][r]=0.f; sma[l][r]=0.f; }

  for (int tt=0; tt<nt; ++tt) {
    const int c  = c0 + tt;
    const int tj = (ti + c) & 63;
    const unsigned short* fng = fnb + (size_t)tj*64*64;
    const float* scg = scb + (size_t)tj*64*12;

    __syncthreads();                      // colacc/fnj/scj safe to overwrite
    #pragma unroll
    for (int q=0;q<2;++q) {               // stage 64 rows x 128B of fn, swizzled
      int idx = tid + q*256;
      int row = idx>>3, seg = idx&7;
      const float4 src = *(const float4*)(fng + (size_t)row*64 + seg*8);
      *(float4*)((char*)fnj + row*128 + ((seg*16) ^ ((row&7)<<4))) = src;
    }
    if (tid < 192) {                      // stage 64 rows x 48B of scalars
      int row = tid/3, seg = tid - row*3;
      *(float4*)(scj + row*12 + seg*4) = *(const float4*)(scg + (size_t)row*12 + seg*4);
    }
    __syncthreads();

    #pragma unroll
    for (int sub=0; sub<4; ++sub) {
      const int jloc = sub*16 + col;
      const int sw = (jloc&7)<<4;
      const char* rowp = (const char*)fnj + jloc*128;
      v8bf b0 = __builtin_bit_cast(v8bf, *(const u16x8*)(rowp + ((g*16) ^ sw)));
      v8bf b1 = __builtin_bit_cast(v8bf, *(const u16x8*)(rowp + ((64 + g*16) ^ sw)));
      v4f j0 = *(const v4f*)(scj + jloc*12);
      v4f j1 = *(const v4f*)(scj + jloc*12 + 4);
      v4f j2 = *(const v4f*)(scj + jloc*12 + 8);

      v4f acc = {0.f,0.f,0.f,0.f};
      acc = __builtin_amdgcn_mfma_f32_16x16x32_bf16(a0, b0, acc, 0,0,0);
      acc = __builtin_amdgcn_mfma_f32_16x16x32_bf16(a1, b1, acc, 0,0,0);

      float cp0=0.f, cp1=0.f, cp2=0.f, cp3=0.f, cp4=0.f, cp5=0.f;

      #pragma unroll
      for (int r=0;r<4;++r) {
        const float fs = acc[r];                    // feature cosine (i=g*4+r, j=jloc)
        const float sf = fhi[r][0]*j0.x + fhi[r][1]*j0.y + fhi[r][2]*j0.z;  // flow cos
        float dcx = ci[r][0]-j0.w, dcy = ci[r][1]-j1.x, dcz = ci[r][2]-j1.y;
        float d2c = fmaf(dcx,dcx, fmaf(dcy,dcy, dcz*dcz));   // >=0 by construction
        const float scl = fmaf(fsqrt(d2c), -INVSQRT3, 1.0f);               // color sim
        float dpx = pi[r][0]-j1.w, dpy = pi[r][1]-j2.x, dpz = pi[r][2]-j2.y;
        float d2p = fmaf(dpx,dpx, fmaf(dpy,dpy, dpz*dpz));
        const float spr = fexp2(fsqrt(d2p) * CPROX);                       // prox sim
        const float fsl = fs * LOG2E;
        const float E2 = fexp2(-fsl);               // exp(-fs), shared by 3 losses
        {
          float tt2 = __builtin_fminf(__builtin_fmaxf(fmaf(sf, GS, GC_FLOW), 0.f), 1.f);
          float gp = tt2*tt2*fmaf(tt2, -2.f, 3.f);  // ~sigmoid(5(s-tau))
          float e1 = fexp2(fsl*gp);                 // exp(fs*g+)
          float e2 = E2*e1;                         // exp(-fs*g-)
          spa[0][r] += e1; sma[0][r] += e2; cp0 += e1; cp1 += e2;
        }
        {
          float tt2 = __builtin_fminf(__builtin_fmaxf(fmaf(scl, GS, GC_COLOR), 0.f), 1.f);
          float gp = tt2*tt2*fmaf(tt2, -2.f, 3.f);
          float e1 = fexp2(fsl*gp);
          float e2 = E2*e1;
          spa[1][r] += e1; sma[1][r] += e2; cp2 += e1; cp3 += e2;
        }
        {
          float tt2 = __builtin_fminf(__builtin_fmaxf(fmaf(spr, GS, GC_PROX), 0.f), 1.f);
          float gp = tt2*tt2*fmaf(tt2, -2.f, 3.f);
          float e1 = fexp2(fsl*gp);
          float e2 = E2*e1;
          spa[2][r] += e1; sma[2][r] += e2; cp4 += e1; cp5 += e2;
        }
      }

      // column partials: reduce the 4 g-groups (same 16 j-columns per group)
      cp0 += __shfl_xor(cp0,16); cp0 += __shfl_xor(cp0,32);
      cp1 += __shfl_xor(cp1,16); cp1 += __shfl_xor(cp1,32);
      cp2 += __shfl_xor(cp2,16); cp2 += __shfl_xor(cp2,32);
      cp3 += __shfl_xor(cp3,16); cp3 += __shfl_xor(cp3,32);
      cp4 += __shfl_xor(cp4,16); cp4 += __shfl_xor(cp4,32);
      cp5 += __shfl_xor(cp5,16); cp5 += __shfl_xor(cp5,32);
      if (lane < 16) {
        float* ca = colacc[w][jloc];
        ca[0]=cp0; ca[1]=cp1; ca[2]=cp2; ca[3]=cp3; ca[4]=cp4; ca[5]=cp5;
      }
    }
    __syncthreads();
    if (c >= 1 && c <= 31) {              // flush columns (diag/antipode: rows only)
      for (int s = tid; s < 384; s += 256) {
        int jl = s/6, kk = s - 6*jl;
        float v = colacc[0][jl][kk]+colacc[1][jl][kk]+colacc[2][jl][kk]+colacc[3][jl][kk];
        part2[(((size_t)b*31 + (c-1))*N_ + tj*64 + jl)*6 + kk] = v;
      }
    }
  }

  // rows: reduce the 16 j-columns held across the 16-lane group
  #pragma unroll
  for (int l=0;l<3;++l)
    #pragma unroll
    for (int r=0;r<4;++r) {
      float a=spa[l][r], cc=sma[l][r];
      #pragma unroll
      for (int d=1; d<16; d<<=1){ a += __shfl_xor(a,d); cc += __shfl_xor(cc,d); }
      spa[l][r]=a; sma[l][r]=cc;
    }
  if (col==0) {
    #pragma unroll
    for (int r=0;r<4;++r) {
      float* o = part_row + (((size_t)b*NCH + k)*N_ + irow0 + g*4 + r)*6;
      o[0]=spa[0][r]; o[1]=sma[0][r];
      o[2]=spa[1][r]; o[3]=sma[1][r];
      o[4]=spa[2][r]; o[5]=sma[2][r];
    }
  }
}

// ---------------- finalize: combine row+col partials, log1p + mean ----------------
extern "C" __global__ __launch_bounds__(256) void fin1_k(
    const float* __restrict__ part_row, const float* __restrict__ part2,
    float* __restrict__ partial)
{
  const int pt = blockIdx.x*256 + threadIdx.x;   // b*N_ + i
  const int b = pt >> 12;
  const int i = pt & (N_-1);
  float s[6] = {0.f,0.f,0.f,0.f,0.f,0.f};
  #pragma unroll
  for (int kc=0;kc<NCH;++kc) {
    const float* pp = part_row + (((size_t)b*NCH + kc)*N_ + i)*6;
    #pragma unroll
    for (int q=0;q<6;++q) s[q] += pp[q];
  }
  for (int c=1;c<=31;++c) {
    const float* pp = part2 + (((size_t)b*31 + (c-1))*N_ + i)*6;
    #pragma unroll
    for (int q=0;q<6;++q) s[q] += pp[q];
  }
  float acc = log1pf(s[0]) + log1pf(s[1]) + log1pf(s[2])
            + log1pf(s[3]) + log1pf(s[4]) + log1pf(s[5]);
  #pragma unroll
  for (int d=32; d; d>>=1) acc += __shfl_xor(acc, d);
  __shared__ float wsum[4];
  if ((threadIdx.x&63)==0) wsum[threadIdx.x>>6] = acc;
  __syncthreads();
  if (threadIdx.x==0) partial[blockIdx.x] = wsum[0]+wsum[1]+wsum[2]+wsum[3];
}

extern "C" __global__ void fin2_k(const float* __restrict__ partial, float* __restrict__ out)
{
  float acc = partial[threadIdx.x];   // 64 threads
  #pragma unroll
  for (int d=32; d; d>>=1) acc += __shfl_xor(acc, d);
  if (threadIdx.x==0) out[0] = -acc * (1.0f/(float)BN_);
}

extern "C" void kernel_launch(void* const* d_in, const int* in_sizes, int n_in,
                              void* d_out, int out_size, void* d_ws, size_t ws_size,
                              hipStream_t stream)
{
  const float* flow  = (const float*)d_in[0];
  const float* color = (const float*)d_in[1];
  const float* coord = (const float*)d_in[2];
  const float* feat  = (const float*)d_in[3];
  char* ws = (char*)d_ws;
  unsigned short* fn = (unsigned short*)ws;                       // 2 MB
  float* scal     = (float*)(ws + 2097152);                       // 768 KB
  float* part_row = (float*)(ws + 2883584);                       // 3 MB  [b][8][N][6]
  float* part2    = (float*)(ws + 6029312);                       // 11.6 MB [b][31][N][6]
  float* partial  = (float*)(ws + 18219008);                      // 256 B
  float* outp = (float*)d_out;
  hipLaunchKernelGGL(prep_k, dim3(BN_/4), dim3(256), 0, stream,
                     flow, color, coord, feat, fn, scal);
  hipLaunchKernelGGL(main_k, dim3(NT*NCH, B_), dim3(256), 0, stream,
                     fn, scal, part_row, part2);
  hipLaunchKernelGGL(fin1_k, dim3(BN_/256), dim3(256), 0, stream,
                     part_row, part2, partial);
  hipLaunchKernelGGL(fin2_k, dim3(1), dim3(64), 0, stream, partial, outp);
}